// Round 6
// baseline (152.822 us; speedup 1.0000x reference)
//
#include <hip/hip_runtime.h>
#include <hip/hip_bf16.h>
#include <cstdint>
#include <cstddef>

// Problem constants
#define BDIM   32768
#define KDIM   2048
#define NDIM   128
#define VHEADS 20
#define PDIM   6
#define RLORA  10

#define BM     16
#define BK2    128
#define NCH    (KDIM / BK2)                 // 16
#define OUT_ELEMS   (BDIM * VHEADS * PDIM)  // 3932160
#define WS_W_BYTES  (KDIM * NDIM * 2)       // 524288

typedef __attribute__((ext_vector_type(8))) __bf16 bf16x8;
typedef __attribute__((ext_vector_type(4))) float f32x4;
typedef __attribute__((ext_vector_type(2))) float f32x2;
typedef __attribute__((ext_vector_type(4))) unsigned int u32x4;

union FragU { bf16x8 b; u32x4 u; };

__device__ __forceinline__ unsigned int cvt_pk_bf16(float lo, float hi) {
  unsigned int r;
  asm("v_cvt_pk_bf16_f32 %0, %1, %2" : "=v"(r) : "v"(lo), "v"(hi));
  return r;
}

__device__ __forceinline__ void gload_lds16(const void* g, void* l) {
  __builtin_amdgcn_global_load_lds(
      (const __attribute__((address_space(1))) void*)(g),
      (__attribute__((address_space(3))) void*)(l), 16, 0, 0);
}

__device__ __forceinline__ float fast_tanh(float x) {
  float ax = fabsf(x);
  float e  = __expf(-2.0f * ax);
  float t  = __fdividef(1.0f - e, 1.0f + e);
  return copysignf(t, x);
}

// ---------------------------------------------------------------------------
// k0: pack We1 f32[2048][128] -> bf16 in B-FRAGMENT-MAJOR order:
//   flat[(((c64*8+nt)*2+ks)*64 + lane)*8 + j] = bf16(We1[k][n])
//   n = nt*16 + (lane&15), k = c64*64 + ks*32 + (lane>>4)*8 + j.
// B-load for (c64,nt,ks) is one coalesced dwordx4 at
//   wp + (c64*16 + nt*2 + ks)*1024B + lane*16B.   (L2-resident, 512 KB)
// Also M = lora_A @ lora_B ([2][120]).
// ---------------------------------------------------------------------------
__global__ __launch_bounds__(256)
void k0_pack(const float* __restrict__ We1,
             const float* __restrict__ lA,
             const float* __restrict__ lB,
             unsigned short* __restrict__ wsw,
             float* __restrict__ wsM) {
  if (blockIdx.x == 128) {
    int t = threadIdx.x;
    if (t < 2 * VHEADS * PDIM) {
      int d  = t / (VHEADS * PDIM);
      int vp = t - d * (VHEADS * PDIM);
      float s = 0.f;
#pragma unroll
      for (int r = 0; r < RLORA; ++r)
        s = fmaf(lA[d * RLORA + r], lB[r * (VHEADS * PDIM) + vp], s);
      wsM[t] = s;  // layout [d][vp]
    }
    return;
  }
  int t    = blockIdx.x * 256 + threadIdx.x;  // 0..32767
  int lane = t & 63;
  int blk  = t >> 6;                          // 0..511
  int ks   = blk & 1;
  int nt   = (blk >> 1) & 7;
  int c    = blk >> 4;
  int n    = nt * 16 + (lane & 15);
  int kb   = c * 64 + ks * 32 + (lane >> 4) * 8;

  unsigned int u[4];
#pragma unroll
  for (int q = 0; q < 4; ++q) {
    float f0 = We1[(size_t)(kb + 2 * q + 0) * NDIM + n];
    float f1 = We1[(size_t)(kb + 2 * q + 1) * NDIM + n];
    __hip_bfloat16 h0 = __float2bfloat16(f0);
    __hip_bfloat16 h1 = __float2bfloat16(f1);
    u[q] = (unsigned int)*reinterpret_cast<unsigned short*>(&h0) |
           ((unsigned int)*reinterpret_cast<unsigned short*>(&h1) << 16);
  }
  *reinterpret_cast<u32x4*>(wsw + (size_t)t * 8) = u32x4{u[0], u[1], u[2], u[3]};
}

// ---------------------------------------------------------------------------
// k1: fused encoder + heads, occupancy-first.
//   2048 blocks x 256 thr (4 waves), BM=16 rows/block, full K per wave.
//   All 4 waves compute the SAME 16 rows; wave wv owns cols wv*32..+31.
//   A: f32 [16][128] = 8 KB/chunk, double-buffered via global_load_lds
//      (2 instr/thread/chunk).  LDS image: k 0-63 at row*256+k*4,
//      k 64-127 at 4096 + row*256 + (k-64)*4.  Fragment reads broadcast
//      within 16-lane groups -> bank-conflict-free, no swizzle needed.
//   B: fragment-packed bf16 direct from L2 (no LDS).
//   LDS ~17 KB/block -> many blocks/CU; block-level TLP hides the
//   per-chunk vmcnt drain.
//   Epilogue: be1/relu/We2/be2 with cross-wave LDS reduce -> z; fused heads.
// ---------------------------------------------------------------------------
__global__ __launch_bounds__(256, 4)
void k1_fused(const float* __restrict__ x,
              const unsigned short* __restrict__ wp,
              const float* __restrict__ be1,
              const float* __restrict__ We2,
              const float* __restrict__ be2,
              const float* __restrict__ W1,
              const float* __restrict__ b1,
              const float* __restrict__ W2,
              const float* __restrict__ b2,
              const float* __restrict__ M,
              float* __restrict__ out,
              float* __restrict__ zout) {
  __shared__ float ldsA[2][2048] __attribute__((aligned(16)));  // 16 KB
  __shared__ float zpart[4][16][2];
  __shared__ float zsh[16][2];

  const int tid  = threadIdx.x;
  const int lane = tid & 63;
  const int wv   = tid >> 6;   // 0..3
  const int l15  = lane & 15;
  const int kgrp = lane >> 4;  // 0..3
  const int blk  = blockIdx.x;

  // A staging source: row = blk*16 + wv*4 + (lane>>4), 16B slot = (lane&15)
  const float* arow = x + (size_t)(blk * BM + wv * 4 + (lane >> 4)) * KDIM
                        + (lane & 15) * 4;

  f32x4 acc[2];
  acc[0] = f32x4{0.f, 0.f, 0.f, 0.f};
  acc[1] = f32x4{0.f, 0.f, 0.f, 0.f};

  auto STAGE = [&](int b, int c) {
    const float* s0 = arow + c * BK2;
    gload_lds16(s0,      &ldsA[b][wv * 256]);          // k 0-63 half
    gload_lds16(s0 + 64, &ldsA[b][1024 + wv * 256]);   // k 64-127 half
  };

  auto COMPUTE = [&](int b, int c) {
    // B fragments (global, L2-hot)
    const char* bb = (const char*)wp + (size_t)c * 32768 + lane * 16;
    FragU bf[2][4];
#pragma unroll
    for (int ntl = 0; ntl < 2; ++ntl) {
      int nt = wv * 2 + ntl;
#pragma unroll
      for (int ks = 0; ks < 4; ++ks) {
        int off = (((ks >> 1) * 16) + nt * 2 + (ks & 1)) * 1024;
        bf[ntl][ks].u = *(const u32x4*)(bb + off);
      }
    }
    // A fragments (LDS, broadcast within 16-lane groups)
    const char* ab = (const char*)&ldsA[b][0] + l15 * 256 + kgrp * 32;
    FragU af[4];
#pragma unroll
    for (int ks = 0; ks < 4; ++ks) {
      const char* p = ab + (ks & 1) * 128 + (ks >> 1) * 4096;
      f32x4 lo = *(const f32x4*)(p);
      f32x4 hi = *(const f32x4*)(p + 16);
      af[ks].u = u32x4{cvt_pk_bf16(lo.x, lo.y), cvt_pk_bf16(lo.z, lo.w),
                       cvt_pk_bf16(hi.x, hi.y), cvt_pk_bf16(hi.z, hi.w)};
    }
#pragma unroll
    for (int ks = 0; ks < 4; ++ks) {
      acc[0] = __builtin_amdgcn_mfma_f32_16x16x32_bf16(af[ks].b, bf[0][ks].b, acc[0], 0, 0, 0);
      acc[1] = __builtin_amdgcn_mfma_f32_16x16x32_bf16(af[ks].b, bf[1][ks].b, acc[1], 0, 0, 0);
    }
  };

  // prologue
  STAGE(0, 0);
  __syncthreads();

#pragma unroll 1
  for (int c = 0; c < NCH; ++c) {
    int b = c & 1;
    if (c + 1 < NCH) STAGE(b ^ 1, c + 1);
    COMPUTE(b, c);
    __syncthreads();
  }

  // ---- epilogue: +be1, relu, @We2 partials (this wave's 32 cols)
  float part[4][2];
#pragma unroll
  for (int j = 0; j < 4; ++j) { part[j][0] = 0.f; part[j][1] = 0.f; }
#pragma unroll
  for (int ntl = 0; ntl < 2; ++ntl) {
    int col = (wv * 2 + ntl) * 16 + l15;
    float bb = be1[col];
    float w0 = We2[col * 2 + 0];
    float w1 = We2[col * 2 + 1];
#pragma unroll
    for (int j = 0; j < 4; ++j) {
      float h = acc[ntl][j] + bb;
      h = h > 0.f ? h : 0.f;
      part[j][0] = fmaf(h, w0, part[j][0]);
      part[j][1] = fmaf(h, w1, part[j][1]);
    }
  }
#pragma unroll
  for (int m = 1; m < 16; m <<= 1) {
#pragma unroll
    for (int j = 0; j < 4; ++j) {
      part[j][0] += __shfl_xor(part[j][0], m, 64);
      part[j][1] += __shfl_xor(part[j][1], m, 64);
    }
  }
  if (l15 == 0) {
#pragma unroll
    for (int j = 0; j < 4; ++j) {
      zpart[wv][kgrp * 4 + j][0] = part[j][0];
      zpart[wv][kgrp * 4 + j][1] = part[j][1];
    }
  }
  __syncthreads();
  if (tid < BM) {
    float s0 = zpart[0][tid][0] + zpart[1][tid][0] + zpart[2][tid][0] +
               zpart[3][tid][0] + be2[0];
    float s1 = zpart[0][tid][1] + zpart[1][tid][1] + zpart[2][tid][1] +
               zpart[3][tid][1] + be2[1];
    zsh[tid][0] = s0;
    zsh[tid][1] = s1;
    f32x2 zz = {s0, s1};
    *(f32x2*)(zout + (size_t)(blk * BM + tid) * 2) = zz;
  }
  __syncthreads();

  // ---- heads: row = tid&15, head slot = tid>>4 (slots 0..15; 0..3 also 16..19)
  const int srow = tid & 15;
  const int slot = tid >> 4;
  float z0 = zsh[srow][0];
  float z1 = zsh[srow][1];
  float* orow = out + (size_t)(blk * BM + srow) * (VHEADS * PDIM);

  auto head = [&](int v) {
    const float* w1a = W1 + (size_t)(v * 2 + 0) * NDIM;
    const float* w1b = W1 + (size_t)(v * 2 + 1) * NDIM;
    const float* bb1 = b1 + (size_t)v * NDIM;
    const float* w2  = W2 + (size_t)v * NDIM * PDIM;

    float p[6] = {0.f, 0.f, 0.f, 0.f, 0.f, 0.f};
#pragma unroll 4
    for (int h = 0; h < NDIM; ++h) {
      float hv = fmaf(z0, w1a[h], fmaf(z1, w1b[h], bb1[h]));
      hv = hv > 0.f ? hv : 0.f;
#pragma unroll
      for (int j = 0; j < 6; ++j) p[j] = fmaf(hv, w2[h * 6 + j], p[j]);
    }
    float o[6];
#pragma unroll
    for (int j = 0; j < 6; ++j) {
      float t1 = fast_tanh(p[j] + b2[v * PDIM + j]);
      float lo = fmaf(z0, M[v * PDIM + j], z1 * M[VHEADS * PDIM + v * PDIM + j]);
      o[j] = fast_tanh(fmaf(0.15f, lo, t1));
    }
    float* op = orow + v * PDIM;
    f32x2 o01 = {o[0], o[1]};
    f32x2 o23 = {o[2], o[3]};
    f32x2 o45 = {o[4], o[5]};
    __builtin_nontemporal_store(o01, (f32x2*)(op + 0));
    __builtin_nontemporal_store(o23, (f32x2*)(op + 2));
    __builtin_nontemporal_store(o45, (f32x2*)(op + 4));
  };

  head(slot);
  if (slot < 4) head(16 + slot);
}

// ---------------------------------------------------------------------------
extern "C" void kernel_launch(void* const* d_in, const int* in_sizes, int n_in,
                              void* d_out, int out_size, void* d_ws, size_t ws_size,
                              hipStream_t stream) {
  const float* x   = (const float*)d_in[0];
  const float* We1 = (const float*)d_in[1];
  const float* be1 = (const float*)d_in[2];
  const float* We2 = (const float*)d_in[3];
  const float* be2 = (const float*)d_in[4];
  const float* W1  = (const float*)d_in[5];
  const float* b1  = (const float*)d_in[6];
  const float* W2  = (const float*)d_in[7];
  const float* b2  = (const float*)d_in[8];
  const float* lA  = (const float*)d_in[9];
  const float* lB  = (const float*)d_in[10];

  float* out  = (float*)d_out;
  float* zout = out + OUT_ELEMS;                       // second tuple output
  unsigned short* wsw = (unsigned short*)d_ws;         // 512 KB bf16 W pack
  float* wsM = (float*)((char*)d_ws + WS_W_BYTES);     // 240 floats

  hipLaunchKernelGGL(k0_pack, dim3(129), dim3(256), 0, stream,
                     We1, lA, lB, wsw, wsM);
  hipLaunchKernelGGL(k1_fused, dim3(BDIM / BM), dim3(256), 0, stream,
                     x, wsw, be1, We2, be2, W1, b1, W2, b2, wsM, out, zout);
}

// Round 7
// 148.947 us; speedup vs baseline: 1.0260x; 1.0260x over previous
//
#include <hip/hip_runtime.h>
#include <hip/hip_bf16.h>
#include <cstdint>
#include <cstddef>

// Problem constants
#define BDIM   32768
#define KDIM   2048
#define NDIM   128
#define VHEADS 20
#define PDIM   6
#define RLORA  10

#define BM     16
#define BK2    128
#define NCH    (KDIM / BK2)                 // 16
#define OUT_ELEMS   (BDIM * VHEADS * PDIM)  // 3932160
#define WS_W_BYTES  (KDIM * NDIM * 2)       // 524288

typedef __attribute__((ext_vector_type(8))) __bf16 bf16x8;
typedef __attribute__((ext_vector_type(4))) float f32x4;
typedef __attribute__((ext_vector_type(2))) float f32x2;
typedef __attribute__((ext_vector_type(4))) unsigned int u32x4;

union FragU { bf16x8 b; u32x4 u; };

__device__ __forceinline__ unsigned int cvt_pk_bf16(float lo, float hi) {
  unsigned int r;
  asm("v_cvt_pk_bf16_f32 %0, %1, %2" : "=v"(r) : "v"(lo), "v"(hi));
  return r;
}

__device__ __forceinline__ void gload_lds16(const void* g, void* l) {
  __builtin_amdgcn_global_load_lds(
      (const __attribute__((address_space(1))) void*)(g),
      (__attribute__((address_space(3))) void*)(l), 16, 0, 0);
}

__device__ __forceinline__ float fast_tanh(float x) {
  float ax = fabsf(x);
  float e  = __expf(-2.0f * ax);
  float t  = __fdividef(1.0f - e, 1.0f + e);
  return copysignf(t, x);
}

// ---------------------------------------------------------------------------
// k0: pack We1 f32[2048][128] -> bf16 in B-FRAGMENT-MAJOR order (unchanged):
//   n = nt*16 + (lane&15), k = c64*64 + ks*32 + (lane>>4)*8 + j.
//   B-load for (c64,nt,ks) = one dwordx4 at wp + (c64*16+nt*2+ks)*1024 + lane*16.
// Also M = lora_A @ lora_B ([2][120]).
// ---------------------------------------------------------------------------
__global__ __launch_bounds__(256)
void k0_pack(const float* __restrict__ We1,
             const float* __restrict__ lA,
             const float* __restrict__ lB,
             unsigned short* __restrict__ wsw,
             float* __restrict__ wsM) {
  if (blockIdx.x == 128) {
    int t = threadIdx.x;
    if (t < 2 * VHEADS * PDIM) {
      int d  = t / (VHEADS * PDIM);
      int vp = t - d * (VHEADS * PDIM);
      float s = 0.f;
#pragma unroll
      for (int r = 0; r < RLORA; ++r)
        s = fmaf(lA[d * RLORA + r], lB[r * (VHEADS * PDIM) + vp], s);
      wsM[t] = s;  // layout [d][vp]
    }
    return;
  }
  int t    = blockIdx.x * 256 + threadIdx.x;  // 0..32767
  int lane = t & 63;
  int blk  = t >> 6;                          // 0..511
  int ks   = blk & 1;
  int nt   = (blk >> 1) & 7;
  int c    = blk >> 4;
  int n    = nt * 16 + (lane & 15);
  int kb   = c * 64 + ks * 32 + (lane >> 4) * 8;

  unsigned int u[4];
#pragma unroll
  for (int q = 0; q < 4; ++q) {
    float f0 = We1[(size_t)(kb + 2 * q + 0) * NDIM + n];
    float f1 = We1[(size_t)(kb + 2 * q + 1) * NDIM + n];
    __hip_bfloat16 h0 = __float2bfloat16(f0);
    __hip_bfloat16 h1 = __float2bfloat16(f1);
    u[q] = (unsigned int)*reinterpret_cast<unsigned short*>(&h0) |
           ((unsigned int)*reinterpret_cast<unsigned short*>(&h1) << 16);
  }
  *reinterpret_cast<u32x4*>(wsw + (size_t)t * 8) = u32x4{u[0], u[1], u[2], u[3]};
}

// ---------------------------------------------------------------------------
// k1: fused encoder + heads, occupancy-first + swizzled A + B-hoist.
//   2048 blocks x 256 thr (4 waves), BM=16 rows/block, full K per wave.
//   All 4 waves compute the SAME 16 rows; wave wv owns cols wv*32..+31.
//   A: f32 [16][128] chunk, double-buffered global_load_lds, LINEAR dest,
//      source pre-swizzled: LDS 16B-granule s of row r = global granule
//      s^(r&7).  Reader XORs identically -> 2-way conflicts (free).
//   B: fragment-packed bf16 direct from L2, loaded to regs BEFORE the
//      chunk barrier so L2 latency hides under the barrier/DMA drain.
//   One __syncthreads per chunk.
//   Epilogue: be1/relu/We2/be2 cross-wave reduce -> z; fused heads.
// ---------------------------------------------------------------------------
__global__ __launch_bounds__(256, 4)
void k1_fused(const float* __restrict__ x,
              const unsigned short* __restrict__ wp,
              const float* __restrict__ be1,
              const float* __restrict__ We2,
              const float* __restrict__ be2,
              const float* __restrict__ W1,
              const float* __restrict__ b1,
              const float* __restrict__ W2,
              const float* __restrict__ b2,
              const float* __restrict__ M,
              float* __restrict__ out,
              float* __restrict__ zout) {
  __shared__ float ldsA[2][2048] __attribute__((aligned(16)));  // 16 KB
  __shared__ float zpart[4][16][2];
  __shared__ float zsh[16][2];

  const int tid  = threadIdx.x;
  const int lane = tid & 63;
  const int wv   = tid >> 6;   // 0..3
  const int l15  = lane & 15;
  const int kgrp = lane >> 4;  // 0..3
  const int blk  = blockIdx.x;

  // A staging: row = wv*4 + (lane>>4), dest granule s = lane&15,
  // source granule s ^ (row&7)  (16B granules within the 64-float half-row)
  const int arow = wv * 4 + (lane >> 4);
  const int sg   = (lane & 15) ^ (arow & 7);
  const float* asrc = x + (size_t)(blk * BM + arow) * KDIM + sg * 4;

  f32x4 acc[2];
  acc[0] = f32x4{0.f, 0.f, 0.f, 0.f};
  acc[1] = f32x4{0.f, 0.f, 0.f, 0.f};

  auto STAGE = [&](int b, int c) {
    const float* s0 = asrc + c * BK2;
    gload_lds16(s0,      &ldsA[b][wv * 256]);          // k 0-63 half
    gload_lds16(s0 + 64, &ldsA[b][1024 + wv * 256]);   // k 64-127 half
  };

  FragU bf[2][4];
  auto BLOAD = [&](int c) {
    const char* bb = (const char*)wp + (size_t)c * 32768 + lane * 16;
#pragma unroll
    for (int ntl = 0; ntl < 2; ++ntl) {
      int nt = wv * 2 + ntl;
#pragma unroll
      for (int ks = 0; ks < 4; ++ks) {
        int off = (((ks >> 1) * 16) + nt * 2 + (ks & 1)) * 1024;
        bf[ntl][ks].u = *(const u32x4*)(bb + off);
      }
    }
  };

  auto COMPUTE = [&](int b) {
    // A fragments (LDS, swizzled read)
    const char* ab = (const char*)&ldsA[b][0] + l15 * 256;
    const int m = (l15 & 7) << 4;
    FragU af[4];
#pragma unroll
    for (int ks = 0; ks < 4; ++ks) {
      int o = ((kgrp * 2 + (ks & 1) * 8) << 4) ^ m;    // swizzled lo-granule
      const char* p = ab + (ks >> 1) * 4096;
      f32x4 lo = *(const f32x4*)(p + o);
      f32x4 hi = *(const f32x4*)(p + (o ^ 16));
      af[ks].u = u32x4{cvt_pk_bf16(lo.x, lo.y), cvt_pk_bf16(lo.z, lo.w),
                       cvt_pk_bf16(hi.x, hi.y), cvt_pk_bf16(hi.z, hi.w)};
    }
#pragma unroll
    for (int ks = 0; ks < 4; ++ks) {
      acc[0] = __builtin_amdgcn_mfma_f32_16x16x32_bf16(af[ks].b, bf[0][ks].b, acc[0], 0, 0, 0);
      acc[1] = __builtin_amdgcn_mfma_f32_16x16x32_bf16(af[ks].b, bf[1][ks].b, acc[1], 0, 0, 0);
    }
  };

  // prologue
  STAGE(0, 0);

#pragma unroll 1
  for (int c = 0; c < NCH; ++c) {
    int b = c & 1;
    BLOAD(c);                 // B regs in flight across the barrier
    __syncthreads();          // A[c] DMA drained (all waves)
    if (c + 1 < NCH) STAGE(b ^ 1, c + 1);   // next A DMA under COMPUTE
    COMPUTE(b);
  }

  // ---- epilogue: +be1, relu, @We2 partials (this wave's 32 cols)
  float part[4][2];
#pragma unroll
  for (int j = 0; j < 4; ++j) { part[j][0] = 0.f; part[j][1] = 0.f; }
#pragma unroll
  for (int ntl = 0; ntl < 2; ++ntl) {
    int col = (wv * 2 + ntl) * 16 + l15;
    float bb = be1[col];
    float w0 = We2[col * 2 + 0];
    float w1 = We2[col * 2 + 1];
#pragma unroll
    for (int j = 0; j < 4; ++j) {
      float h = acc[ntl][j] + bb;
      h = h > 0.f ? h : 0.f;
      part[j][0] = fmaf(h, w0, part[j][0]);
      part[j][1] = fmaf(h, w1, part[j][1]);
    }
  }
#pragma unroll
  for (int m = 1; m < 16; m <<= 1) {
#pragma unroll
    for (int j = 0; j < 4; ++j) {
      part[j][0] += __shfl_xor(part[j][0], m, 64);
      part[j][1] += __shfl_xor(part[j][1], m, 64);
    }
  }
  if (l15 == 0) {
#pragma unroll
    for (int j = 0; j < 4; ++j) {
      zpart[wv][kgrp * 4 + j][0] = part[j][0];
      zpart[wv][kgrp * 4 + j][1] = part[j][1];
    }
  }
  __syncthreads();
  if (tid < BM) {
    float s0 = zpart[0][tid][0] + zpart[1][tid][0] + zpart[2][tid][0] +
               zpart[3][tid][0] + be2[0];
    float s1 = zpart[0][tid][1] + zpart[1][tid][1] + zpart[2][tid][1] +
               zpart[3][tid][1] + be2[1];
    zsh[tid][0] = s0;
    zsh[tid][1] = s1;
    f32x2 zz = {s0, s1};
    *(f32x2*)(zout + (size_t)(blk * BM + tid) * 2) = zz;
  }
  __syncthreads();

  // ---- heads: row = tid&15, head slot = tid>>4 (slots 0..15; 0..3 also 16..19)
  const int srow = tid & 15;
  const int slot = tid >> 4;
  float z0 = zsh[srow][0];
  float z1 = zsh[srow][1];
  float* orow = out + (size_t)(blk * BM + srow) * (VHEADS * PDIM);

  auto head = [&](int v) {
    const float* w1a = W1 + (size_t)(v * 2 + 0) * NDIM;
    const float* w1b = W1 + (size_t)(v * 2 + 1) * NDIM;
    const float* bb1 = b1 + (size_t)v * NDIM;
    const float* w2  = W2 + (size_t)v * NDIM * PDIM;

    float p[6] = {0.f, 0.f, 0.f, 0.f, 0.f, 0.f};
#pragma unroll 4
    for (int h = 0; h < NDIM; ++h) {
      float hv = fmaf(z0, w1a[h], fmaf(z1, w1b[h], bb1[h]));
      hv = hv > 0.f ? hv : 0.f;
#pragma unroll
      for (int j = 0; j < 6; ++j) p[j] = fmaf(hv, w2[h * 6 + j], p[j]);
    }
    float o[6];
#pragma unroll
    for (int j = 0; j < 6; ++j) {
      float t1 = fast_tanh(p[j] + b2[v * PDIM + j]);
      float lo = fmaf(z0, M[v * PDIM + j], z1 * M[VHEADS * PDIM + v * PDIM + j]);
      o[j] = fast_tanh(fmaf(0.15f, lo, t1));
    }
    float* op = orow + v * PDIM;
    f32x2 o01 = {o[0], o[1]};
    f32x2 o23 = {o[2], o[3]};
    f32x2 o45 = {o[4], o[5]};
    __builtin_nontemporal_store(o01, (f32x2*)(op + 0));
    __builtin_nontemporal_store(o23, (f32x2*)(op + 2));
    __builtin_nontemporal_store(o45, (f32x2*)(op + 4));
  };

  head(slot);
  if (slot < 4) head(16 + slot);
}

// ---------------------------------------------------------------------------
extern "C" void kernel_launch(void* const* d_in, const int* in_sizes, int n_in,
                              void* d_out, int out_size, void* d_ws, size_t ws_size,
                              hipStream_t stream) {
  const float* x   = (const float*)d_in[0];
  const float* We1 = (const float*)d_in[1];
  const float* be1 = (const float*)d_in[2];
  const float* We2 = (const float*)d_in[3];
  const float* be2 = (const float*)d_in[4];
  const float* W1  = (const float*)d_in[5];
  const float* b1  = (const float*)d_in[6];
  const float* W2  = (const float*)d_in[7];
  const float* b2  = (const float*)d_in[8];
  const float* lA  = (const float*)d_in[9];
  const float* lB  = (const float*)d_in[10];

  float* out  = (float*)d_out;
  float* zout = out + OUT_ELEMS;                       // second tuple output
  unsigned short* wsw = (unsigned short*)d_ws;         // 512 KB bf16 W pack
  float* wsM = (float*)((char*)d_ws + WS_W_BYTES);     // 240 floats

  hipLaunchKernelGGL(k0_pack, dim3(129), dim3(256), 0, stream,
                     We1, lA, lB, wsw, wsM);
  hipLaunchKernelGGL(k1_fused, dim3(BDIM / BM), dim3(256), 0, stream,
                     x, wsw, be1, We2, be2, W1, b1, W2, b2, wsM, out, zout);
}